// Round 1
// baseline (339.473 us; speedup 1.0000x reference)
//
#include <hip/hip_runtime.h>
#include <hip/hip_bf16.h>

#define IH   96
#define IW   320
#define NB   4
#define CIN  128
#define COUT 128
#define NKP  9
#define HoWo (IH*IW)

typedef float f32x4  __attribute__((ext_vector_type(4)));
typedef short bf16x8 __attribute__((ext_vector_type(8)));

__device__ __forceinline__ float bflo(unsigned u) { return __uint_as_float(u << 16); }
__device__ __forceinline__ float bfhi(unsigned u) { return __uint_as_float(u & 0xffff0000u); }
// RNE f32 -> bf16 bits
__device__ __forceinline__ unsigned short f2bf(float f) {
    unsigned u = __float_as_uint(f);
    u += 0x7fffu + ((u >> 16) & 1u);
    return (unsigned short)(u >> 16);
}

// ---------- pre-pass 1: NCHW f32 -> NHWC bf16 ----------
__global__ __launch_bounds__(256) void k_transpose(const float* __restrict__ in,
                                                   unsigned short* __restrict__ outb) {
    __shared__ float tile[32][129];
    int bid = blockIdx.x;            // b*IH*10 + y*10 + xc
    int xc = bid % 10;
    int by = bid / 10;
    int y = by % IH;
    int b = by / IH;
    int x0 = xc * 32;
    int tid = threadIdx.x;

    const float* src = in + (size_t)b * CIN * IH * IW + (size_t)y * IW + x0;
#pragma unroll
    for (int i = 0; i < 16; ++i) {
        int idx = tid + 256 * i;
        int c = idx >> 5, xl = idx & 31;
        tile[xl][c] = src[(size_t)c * (IH * IW) + xl];
    }
    __syncthreads();
    unsigned* dst32 = (unsigned*)(outb + ((size_t)(b * IH + y) * IW + x0) * CIN);
#pragma unroll
    for (int i = 0; i < 8; ++i) {
        int idx = tid + 256 * i;
        int c2 = idx & 63, xl = idx >> 6;
        unsigned lo = f2bf(tile[xl][2 * c2]);
        unsigned hi = f2bf(tile[xl][2 * c2 + 1]);
        dst32[xl * 64 + c2] = lo | (hi << 16);
    }
}

// ---------- pre-pass 2: weight [Cout][Cin][9] f32 -> [kp][Cout][Cin] bf16 ----------
__global__ __launch_bounds__(256) void k_prepack(const float* __restrict__ w,
                                                 unsigned short* __restrict__ wb) {
    int idx = blockIdx.x * 256 + threadIdx.x;    // 9*128*128 = 147456 exact
    int kp = idx >> 14;
    int cout = (idx >> 7) & 127;
    int c = idx & 127;
    wb[idx] = f2bf(w[(cout * CIN + c) * NKP + kp]);
}

// ---------- main fused kernel ----------
__global__ __launch_bounds__(256, 2) void k_main(const float* __restrict__ off,
                                                 const unsigned short* __restrict__ nhwc,
                                                 const unsigned short* __restrict__ wb,
                                                 float* __restrict__ out) {
    __shared__ unsigned colbuf[64 * 64];   // 64 positions x 128 bf16 (as 64 dwords), XOR-swizzled

    const int tid  = threadIdx.x;
    const int lane = tid & 63;
    const int wv   = tid >> 6;
    const int n0   = blockIdx.x * 64;
    const int b    = n0 / HoWo;
    const int rem  = n0 - b * HoWo;
    const int ho   = rem / IW;
    const int wo0  = rem - ho * IW;

    const unsigned* fbase = (const unsigned*)nhwc;   // 64 dwords per pixel

    f32x4 acc[2][4];
#pragma unroll
    for (int mi = 0; mi < 2; ++mi)
#pragma unroll
        for (int nj = 0; nj < 4; ++nj)
            acc[mi][nj] = (f32x4){0.f, 0.f, 0.f, 0.f};

    for (int kp = 0; kp < NKP; ++kp) {
        // ---- sampling phase: this wave fills positions [16*wv, 16*wv+16) ----
        const float* offy = off + ((size_t)(b * 18 + 2 * kp) * IH + ho) * IW + wo0;
        const float* offx = offy + (size_t)IH * IW;
        const int ky = kp / 3, kx = kp - 3 * (kp / 3);
#pragma unroll 4
        for (int i = 0; i < 16; ++i) {
            int p = (wv << 4) + i;
            float dy = offy[p];
            float dx = offx[p];
            float py = (float)(ho - 1 + ky) + dy;
            float px = (float)(wo0 + p - 1 + kx) + dx;
            float y0f = floorf(py), x0f = floorf(px);
            float wy1 = py - y0f, wx1 = px - x0f;
            float wy0 = 1.f - wy1, wx0 = 1.f - wx1;
            int y0 = (int)y0f, x0i = (int)x0f;
            int y1 = y0 + 1, x1 = x0i + 1;
            // fold zero-padding validity into the weights
            wy0 *= (y0 >= 0 && y0 < IH) ? 1.f : 0.f;
            wy1 *= (y1 >= 0 && y1 < IH) ? 1.f : 0.f;
            wx0 *= (x0i >= 0 && x0i < IW) ? 1.f : 0.f;
            wx1 *= (x1 >= 0 && x1 < IW) ? 1.f : 0.f;
            float w00 = wy0 * wx0, w01 = wy0 * wx1;
            float w10 = wy1 * wx0, w11 = wy1 * wx1;
            int yc0 = min(max(y0, 0), IH - 1), yc1 = min(max(y1, 0), IH - 1);
            int xc0 = min(max(x0i, 0), IW - 1), xc1 = min(max(x1, 0), IW - 1);
            int r0 = (b * IH + yc0) * IW, r1 = (b * IH + yc1) * IW;
            unsigned u00 = fbase[(size_t)(r0 + xc0) * 64 + lane];
            unsigned u01 = fbase[(size_t)(r0 + xc1) * 64 + lane];
            unsigned u10 = fbase[(size_t)(r1 + xc0) * 64 + lane];
            unsigned u11 = fbase[(size_t)(r1 + xc1) * 64 + lane];
            float slo = w00 * bflo(u00) + w01 * bflo(u01) + w10 * bflo(u10) + w11 * bflo(u11);
            float shi = w00 * bfhi(u00) + w01 * bfhi(u01) + w10 * bfhi(u10) + w11 * bfhi(u11);
            unsigned res = (unsigned)f2bf(slo) | ((unsigned)f2bf(shi) << 16);
            colbuf[(p << 6) + (lane ^ ((p & 7) << 2))] = res;   // swizzled dword index
        }
        __syncthreads();

        // ---- MFMA phase: wave tile = 32 Cout rows x 64 positions ----
        const unsigned short* wkbase =
            wb + (size_t)kp * COUT * CIN + (size_t)(wv * 32 + (lane & 15)) * CIN + 8 * (lane >> 4);
#pragma unroll
        for (int c0 = 0; c0 < CIN; c0 += 32) {
            bf16x8 a0 = *(const bf16x8*)(wkbase + c0);
            bf16x8 a1 = *(const bf16x8*)(wkbase + 16 * CIN + c0);
            int cb = (c0 >> 1) + 4 * (lane >> 4);   // dword base within a position's row
#pragma unroll
            for (int nj = 0; nj < 4; ++nj) {
                int pos = nj * 16 + (lane & 15);
                bf16x8 bfr = *(const bf16x8*)(&colbuf[(pos << 6) + (cb ^ ((pos & 7) << 2))]);
                acc[0][nj] = __builtin_amdgcn_mfma_f32_16x16x32_bf16(a0, bfr, acc[0][nj], 0, 0, 0);
                acc[1][nj] = __builtin_amdgcn_mfma_f32_16x16x32_bf16(a1, bfr, acc[1][nj], 0, 0, 0);
            }
        }
        __syncthreads();
    }

    // ---- epilogue: C/D layout col=lane&15, row=(lane>>4)*4+r (m89) ----
#pragma unroll
    for (int mi = 0; mi < 2; ++mi) {
#pragma unroll
        for (int nj = 0; nj < 4; ++nj) {
            int cout = wv * 32 + mi * 16 + ((lane >> 4) << 2);
            int wo = wo0 + nj * 16 + (lane & 15);
            float* op = out + ((size_t)(b * COUT + cout) * IH + ho) * IW + wo;
#pragma unroll
            for (int r = 0; r < 4; ++r)
                op[(size_t)r * IH * IW] = acc[mi][nj][r];
        }
    }
}

extern "C" void kernel_launch(void* const* d_in, const int* in_sizes, int n_in,
                              void* d_out, int out_size, void* d_ws, size_t ws_size,
                              hipStream_t stream) {
    const float* features = (const float*)d_in[0];
    const float* offsets  = (const float*)d_in[1];
    const float* weight   = (const float*)d_in[2];
    float* out = (float*)d_out;

    unsigned short* nhwc = (unsigned short*)d_ws;                       // 31,457,280 B
    unsigned short* wbuf = (unsigned short*)((char*)d_ws + (size_t)NB * IH * IW * CIN * 2);

    hipLaunchKernelGGL(k_transpose, dim3(NB * IH * (IW / 32)), dim3(256), 0, stream, features, nhwc);
    hipLaunchKernelGGL(k_prepack, dim3(576), dim3(256), 0, stream, weight, wbuf);
    hipLaunchKernelGGL(k_main, dim3((NB * HoWo) / 64), dim3(256), 0, stream, offsets, nhwc, wbuf, out);
}

// Round 2
// 249.204 us; speedup vs baseline: 1.3622x; 1.3622x over previous
//
#include <hip/hip_runtime.h>
#include <hip/hip_fp16.h>

#define IH   96
#define IW   320
#define NB   4
#define CIN  128
#define COUT 128
#define NKP  9
#define HW   (IH*IW)

typedef float    f32x4 __attribute__((ext_vector_type(4)));
typedef _Float16 f16x8 __attribute__((ext_vector_type(8)));

// ---------- pre-pass 1: NCHW f32 -> NHWC f16 (channel pairs packed in dwords) ----------
__global__ __launch_bounds__(256) void k_transpose(const float* __restrict__ in,
                                                   unsigned* __restrict__ dst32) {
    __shared__ float tile[32][129];
    int bid = blockIdx.x;            // b*IH*10 + y*10 + xc
    int xc = bid % 10;
    int by = bid / 10;
    int y = by % IH;
    int b = by / IH;
    int x0 = xc * 32;
    int tid = threadIdx.x;

    const float* src = in + (size_t)b * CIN * HW + (size_t)y * IW + x0;
#pragma unroll
    for (int i = 0; i < 16; ++i) {
        int idx = tid + 256 * i;
        int c = idx >> 5, xl = idx & 31;
        tile[xl][c] = src[(size_t)c * HW + xl];
    }
    __syncthreads();
    unsigned* d = dst32 + ((size_t)(b * IH + y) * IW + x0) * 64;
#pragma unroll
    for (int i = 0; i < 8; ++i) {
        int idx = tid + 256 * i;
        int c2 = idx & 63, xl = idx >> 6;
        __half2 p;
        p.x = __float2half(tile[xl][2 * c2]);
        p.y = __float2half(tile[xl][2 * c2 + 1]);
        d[xl * 64 + c2] = *(unsigned*)&p;
    }
}

// ---------- pre-pass 2: weight [Cout][Cin][9] f32 -> [kp][Cout][Cin] f16 ----------
__global__ __launch_bounds__(256) void k_prepack(const float* __restrict__ w,
                                                 _Float16* __restrict__ wb) {
    int idx = blockIdx.x * 256 + threadIdx.x;    // 9*128*128 = 147456 exact
    int kp = idx >> 14;
    int cout = (idx >> 7) & 127;
    int c = idx & 127;
    wb[idx] = (_Float16)w[(cout * CIN + c) * NKP + kp];
}

// ---------- pre-pass 3: per-(pos,kp) sampling metadata ----------
// 32B/item: {w00,w01,w10,w11 as duplicated half2} {4 pixel byte-offsets}
__global__ __launch_bounds__(256) void k_meta(const float* __restrict__ off,
                                              uint4* __restrict__ meta) {
    int idx = blockIdx.x * 256 + threadIdx.x;    // ((b*9+kp)*96+ho)*320+wo, exact
    int wo = idx % IW;
    int t = idx / IW;
    int ho = t % IH;
    t /= IH;
    int kp = t % NKP;
    int b = t / NKP;

    float dy = off[((size_t)(b * 18 + 2 * kp) * IH + ho) * IW + wo];
    float dx = off[((size_t)(b * 18 + 2 * kp + 1) * IH + ho) * IW + wo];
    int ky = kp / 3, kx = kp - 3 * (kp / 3);
    float py = (float)(ho - 1 + ky) + dy;
    float px = (float)(wo - 1 + kx) + dx;
    float y0f = floorf(py), x0f = floorf(px);
    float wy1 = py - y0f, wx1 = px - x0f;
    float wy0 = 1.f - wy1, wx0 = 1.f - wx1;
    int y0 = (int)y0f, x0 = (int)x0f, y1 = y0 + 1, x1 = x0 + 1;
    wy0 = (y0 >= 0 && y0 < IH) ? wy0 : 0.f;
    wy1 = (y1 >= 0 && y1 < IH) ? wy1 : 0.f;
    wx0 = (x0 >= 0 && x0 < IW) ? wx0 : 0.f;
    wx1 = (x1 >= 0 && x1 < IW) ? wx1 : 0.f;
    int yc0 = min(max(y0, 0), IH - 1), yc1 = min(max(y1, 0), IH - 1);
    int xc0 = min(max(x0, 0), IW - 1), xc1 = min(max(x1, 0), IW - 1);
    unsigned r0 = (unsigned)((b * IH + yc0) * IW);
    unsigned r1 = (unsigned)((b * IH + yc1) * IW);

    auto pk = [](float w) {
        __half h = __float2half(w);
        __half2 p; p.x = h; p.y = h;
        return *(unsigned*)&p;
    };
    uint4 m0 = {pk(wy0 * wx0), pk(wy0 * wx1), pk(wy1 * wx0), pk(wy1 * wx1)};
    uint4 m1 = {(r0 + (unsigned)xc0) << 8, (r0 + (unsigned)xc1) << 8,
                (r1 + (unsigned)xc0) << 8, (r1 + (unsigned)xc1) << 8};
    meta[(size_t)idx * 2] = m0;
    meta[(size_t)idx * 2 + 1] = m1;
}

// ---------- main fused kernel ----------
__global__ __launch_bounds__(256, 4) void k_main(const uint4* __restrict__ meta,
                                                 const char* __restrict__ fb,
                                                 const _Float16* __restrict__ wb,
                                                 float* __restrict__ out) {
    __shared__ unsigned colbuf[64 * 64];   // 64 positions x 128 f16 (as 64 dwords), XOR-swizzled

    const int tid  = threadIdx.x;
    const int lane = tid & 63;
    const int wv   = tid >> 6;
    // XCD-aware chunked swizzle: grid 1920 = 8 XCDs x 240 contiguous blocks
    int bid = (blockIdx.x & 7) * 240 + (blockIdx.x >> 3);
    const int n0   = bid * 64;
    const int b    = n0 / HW;
    const int rem  = n0 - b * HW;
    const int ho   = rem / IW;
    const int wo0  = rem - ho * IW;
    const int lane4 = lane << 2;

    f32x4 acc[2][4];
#pragma unroll
    for (int mi = 0; mi < 2; ++mi)
#pragma unroll
        for (int nj = 0; nj < 4; ++nj)
            acc[mi][nj] = (f32x4){0.f, 0.f, 0.f, 0.f};

    for (int kp = 0; kp < NKP; ++kp) {
        const int itemBase = ((b * NKP + kp) * IH + ho) * IW + wo0;
        // ---- sampling: wave fills positions [16*wv, 16*wv+16); meta is wave-uniform ----
#pragma unroll 4
        for (int i = 0; i < 16; ++i) {
            int p = (wv << 4) + i;
            int it = __builtin_amdgcn_readfirstlane(itemBase + p);
            uint4 mw = meta[(size_t)it * 2];       // s_load: 4 duplicated half2 weights
            uint4 ma = meta[(size_t)it * 2 + 1];   // s_load: 4 pixel byte offsets
            __half2 u00 = *(const __half2*)(fb + ma.x + lane4);
            __half2 u01 = *(const __half2*)(fb + ma.y + lane4);
            __half2 u10 = *(const __half2*)(fb + ma.z + lane4);
            __half2 u11 = *(const __half2*)(fb + ma.w + lane4);
            __half2 s = __hmul2(*(const __half2*)&mw.x, u00);
            s = __hfma2(*(const __half2*)&mw.y, u01, s);
            s = __hfma2(*(const __half2*)&mw.z, u10, s);
            s = __hfma2(*(const __half2*)&mw.w, u11, s);
            colbuf[(p << 6) + (lane ^ ((p & 7) << 2))] = *(unsigned*)&s;
        }
        __syncthreads();

        // ---- MFMA: wave tile = 32 Cout rows x 64 positions ----
        const _Float16* wkbase =
            wb + (size_t)kp * COUT * CIN + (size_t)(wv * 32 + (lane & 15)) * CIN + 8 * (lane >> 4);
#pragma unroll
        for (int c0 = 0; c0 < CIN; c0 += 32) {
            f16x8 a0 = *(const f16x8*)(wkbase + c0);
            f16x8 a1 = *(const f16x8*)(wkbase + 16 * CIN + c0);
            int cb = (c0 >> 1) + 4 * (lane >> 4);   // dword base within a position's row
#pragma unroll
            for (int nj = 0; nj < 4; ++nj) {
                int pos = nj * 16 + (lane & 15);
                f16x8 bfr = *(const f16x8*)(&colbuf[(pos << 6) + (cb ^ ((pos & 7) << 2))]);
                acc[0][nj] = __builtin_amdgcn_mfma_f32_16x16x32_f16(a0, bfr, acc[0][nj], 0, 0, 0);
                acc[1][nj] = __builtin_amdgcn_mfma_f32_16x16x32_f16(a1, bfr, acc[1][nj], 0, 0, 0);
            }
        }
        __syncthreads();
    }

    // ---- epilogue: C/D layout col=lane&15, row=(lane>>4)*4+r ----
#pragma unroll
    for (int mi = 0; mi < 2; ++mi) {
#pragma unroll
        for (int nj = 0; nj < 4; ++nj) {
            int cout = wv * 32 + mi * 16 + ((lane >> 4) << 2);
            int wo = wo0 + nj * 16 + (lane & 15);
            float* op = out + ((size_t)(b * COUT + cout) * IH + ho) * IW + wo;
#pragma unroll
            for (int r = 0; r < 4; ++r)
                op[(size_t)r * HW] = acc[mi][nj][r];
        }
    }
}

extern "C" void kernel_launch(void* const* d_in, const int* in_sizes, int n_in,
                              void* d_out, int out_size, void* d_ws, size_t ws_size,
                              hipStream_t stream) {
    const float* features = (const float*)d_in[0];
    const float* offsets  = (const float*)d_in[1];
    const float* weight   = (const float*)d_in[2];
    float* out = (float*)d_out;

    // workspace layout
    unsigned*  nhwc = (unsigned*)d_ws;                                    // 31,457,280 B
    _Float16*  wbuf = (_Float16*)((char*)d_ws + (size_t)NB * HW * CIN * 2);
    uint4*     meta = (uint4*)((char*)d_ws + (size_t)NB * HW * CIN * 2 + 294912); // 35,389,440 B

    hipLaunchKernelGGL(k_transpose, dim3(NB * IH * (IW / 32)), dim3(256), 0, stream, features, nhwc);
    hipLaunchKernelGGL(k_prepack, dim3(576), dim3(256), 0, stream, weight, wbuf);
    hipLaunchKernelGGL(k_meta, dim3(NB * NKP * IH * IW / 256), dim3(256), 0, stream, offsets, meta);
    hipLaunchKernelGGL(k_main, dim3((NB * HW) / 64), dim3(256), 0, stream,
                       meta, (const char*)nhwc, wbuf, out);
}